// Round 3
// baseline (15863.313 us; speedup 1.0000x reference)
//
#include <hip/hip_runtime.h>
#include <hip/hip_bf16.h>

#define BB 64
#define TT 32
#define VV 12000
#define EE 512
#define FF 2048
#define CDIM 128
#define HH 1024
#define LL 49
#define XHLEN 3712   /* E + F + C + H */
#define XKLEN 2688   /* E + F + C */

// ---------------------------------------------------------------------------
// Generic tiled GEMM:  C[M,N] (+)= A[M,K] @ W[N,K]^T + bias[N]
// A row-major with stride lda; W row-major [N][K]; M must be multiple of 64,
// K multiple of 16. Grid: (ceil(N/32), M/64), 256 threads.
// ---------------------------------------------------------------------------
template<bool ACCUM>
__global__ __launch_bounds__(256) void gemm_k(
    const float* __restrict__ A, int lda,
    const float* __restrict__ W,
    const float* __restrict__ bias,
    float* __restrict__ C, int ldc,
    int N, int K)
{
  __shared__ float As[16][64];
  __shared__ float Bs[16][32];
  const int tid = threadIdx.x;
  const int tx = tid & 15, ty = tid >> 4;       // tx -> n (x2), ty -> m (x4)
  const int m0 = blockIdx.y * 64, n0 = blockIdx.x * 32;
  float acc[4][2] = {};
  const int ra = tid >> 2, ca = (tid & 3) << 2; // A: 4 consecutive k per thread
  const int rb = tid >> 3, cb = (tid & 7) << 1; // W: 2 consecutive k per thread

  for (int k0 = 0; k0 < K; k0 += 16) {
    float4 av = *(const float4*)&A[(size_t)(m0 + ra) * lda + k0 + ca];
    float2 wv = make_float2(0.f, 0.f);
    if (n0 + rb < N) wv = *(const float2*)&W[(size_t)(n0 + rb) * K + k0 + cb];
    __syncthreads();
    As[ca + 0][ra] = av.x; As[ca + 1][ra] = av.y;
    As[ca + 2][ra] = av.z; As[ca + 3][ra] = av.w;
    Bs[cb + 0][rb] = wv.x; Bs[cb + 1][rb] = wv.y;
    __syncthreads();
#pragma unroll
    for (int k = 0; k < 16; ++k) {
      float4 a = *(const float4*)&As[k][ty * 4];
      float2 b = *(const float2*)&Bs[k][tx * 2];
      acc[0][0] += a.x * b.x; acc[0][1] += a.x * b.y;
      acc[1][0] += a.y * b.x; acc[1][1] += a.y * b.y;
      acc[2][0] += a.z * b.x; acc[2][1] += a.z * b.y;
      acc[3][0] += a.w * b.x; acc[3][1] += a.w * b.y;
    }
  }
#pragma unroll
  for (int i = 0; i < 4; ++i) {
    int m = m0 + ty * 4 + i;
#pragma unroll
    for (int j = 0; j < 2; ++j) {
      int n = n0 + tx * 2 + j;
      if (n < N) {
        float v = acc[i][j] + (bias ? bias[n] : 0.f);
        float* p = &C[(size_t)m * ldc + n];
        if (ACCUM) *p += v; else *p = v;
      }
    }
  }
}

// ---------------------------------------------------------------------------
// Tiled transpose: out[C][R] = in[R][C]^T. Grid (C/32, R/32), 256 threads.
// ---------------------------------------------------------------------------
__global__ __launch_bounds__(256) void transpose_k(
    const float* __restrict__ in, float* __restrict__ out, int R, int C)
{
  __shared__ float tile[32][33];
  int bc = blockIdx.x * 32, br = blockIdx.y * 32;
  int tx = threadIdx.x & 31, ty4 = (threadIdx.x >> 5) << 2;
#pragma unroll
  for (int i = 0; i < 4; ++i) {
    int r = br + ty4 + i, c = bc + tx;
    tile[ty4 + i][tx] = (r < R && c < C) ? in[(size_t)r * C + c] : 0.f;
  }
  __syncthreads();
#pragma unroll
  for (int i = 0; i < 4; ++i) {
    int oc = bc + ty4 + i, orr = br + tx;
    if (oc < C && orr < R) out[(size_t)oc * R + orr] = tile[tx][ty4 + i];
  }
}

// mean over L of features -> mean_feat[B][F]. Grid 512 x 256 threads.
__global__ __launch_bounds__(256) void mean_k(
    const float* __restrict__ feat, float* __restrict__ mean_feat)
{
  int idx = blockIdx.x * 256 + threadIdx.x;    // B*F = 131072
  int b = idx >> 11, f = idx & 2047;
  float s = 0.f;
#pragma unroll
  for (int l = 0; l < LL; ++l) s += feat[((size_t)b * LL + l) * FF + f];
  mean_feat[idx] = s * (1.f / 49.f);
}

// combined gate bias + category slot of xh. Grid 32 x 256.
__global__ __launch_bounds__(256) void setup_k(
    const float* __restrict__ b_ih, const float* __restrict__ b_hh,
    float* __restrict__ bg,
    const float* __restrict__ cat, float* __restrict__ xh)
{
  int idx = blockIdx.x * 256 + threadIdx.x;
  if (idx < 4096) bg[idx] = b_ih[idx] + b_hh[idx];
  if (idx < BB * CDIM) {
    int b = idx >> 7, j = idx & 127;
    xh[(size_t)b * XHLEN + EE + FF + j] = cat[idx];
  }
}

// Fused attention: scores (tanh), softmax, context, plus embedding gather.
// One block per batch row b. Grid 64 x 256.
__global__ __launch_bounds__(256) void attn_k(
    const float* __restrict__ feat_proj, const float* __restrict__ hU,
    const float* __restrict__ att_v, const float* __restrict__ features,
    const int* __restrict__ captions, const float* __restrict__ emb,
    float* __restrict__ xh, float* __restrict__ w_out, int t)
{
  int b = blockIdx.x;
  __shared__ float s_w[LL];
  int tid = threadIdx.x;
  int wave = tid >> 6, lane = tid & 63;

  // scores: l striped over the 4 waves; each wave reduces over a=0..1023
  for (int l = wave; l < LL; l += 4) {
    const float* fp = feat_proj + ((size_t)b * LL + l) * HH;
    const float* hu = hU + (size_t)b * HH;
    float acc = 0.f;
    for (int a = lane; a < HH; a += 64)
      acc += tanhf(fp[a] + hu[a]) * att_v[a];
#pragma unroll
    for (int off = 32; off > 0; off >>= 1) acc += __shfl_down(acc, off);
    if (lane == 0) s_w[l] = acc;
  }
  __syncthreads();

  // softmax over L=49 in wave 0
  if (wave == 0) {
    float v = (lane < LL) ? s_w[lane] : -1e30f;
    float m = v;
#pragma unroll
    for (int off = 32; off > 0; off >>= 1) m = fmaxf(m, __shfl_xor(m, off));
    float e = (lane < LL) ? expf(v - m) : 0.f;
    float s = e;
#pragma unroll
    for (int off = 32; off > 0; off >>= 1) s += __shfl_xor(s, off);
    float w = e / s;
    if (lane < LL) {
      s_w[lane] = w;
      w_out[((size_t)b * TT + t) * LL + lane] = w;
    }
  }
  __syncthreads();

  // context[b][f] = sum_l w[l] * features[b][l][f]  -> xh context slot
  for (int f = tid; f < FF; f += 256) {
    float acc = 0.f;
#pragma unroll
    for (int l = 0; l < LL; ++l)
      acc += s_w[l] * features[((size_t)b * LL + l) * FF + f];
    xh[(size_t)b * XHLEN + EE + f] = acc;
  }

  // embedding gather -> xh emb slot
  int cap = captions[b * TT + t];
  for (int j = tid; j < EE; j += 256)
    xh[(size_t)b * XHLEN + j] = emb[(size_t)cap * EE + j];
}

// LSTM cell elementwise. Grid 256 x 256 (64*1024 elements).
__global__ __launch_bounds__(256) void lstm_k(
    const float* __restrict__ gates, float* __restrict__ c,
    float* __restrict__ xh)
{
  int idx = blockIdx.x * 256 + threadIdx.x;   // B*H
  int b = idx >> 10, j = idx & 1023;
  const float* g = gates + (size_t)b * 4096;
  float ig = g[j], fg = g[HH + j], gg = g[2 * HH + j], og = g[3 * HH + j];
  float si = 1.f / (1.f + expf(-ig));
  float sf = 1.f / (1.f + expf(-fg));
  float so = 1.f / (1.f + expf(-og));
  float cc = sf * c[idx] + si * tanhf(gg);
  float hh = so * tanhf(cc);
  c[idx] = cc;
  xh[(size_t)b * XHLEN + XKLEN + j] = hh;
}

extern "C" void kernel_launch(void* const* d_in, const int* in_sizes, int n_in,
                              void* d_out, int out_size, void* d_ws, size_t ws_size,
                              hipStream_t stream) {
  const int*   captions = (const int*)  d_in[0];
  const float* features = (const float*)d_in[1];
  const float* category = (const float*)d_in[2];
  const float* emb      = (const float*)d_in[3];
  const float* W_ih     = (const float*)d_in[4];
  const float* b_ih     = (const float*)d_in[5];
  const float* W_hh     = (const float*)d_in[6];
  const float* b_hh     = (const float*)d_in[7];
  const float* fc_W     = (const float*)d_in[8];
  const float* fc_b     = (const float*)d_in[9];
  const float* Wh0      = (const float*)d_in[10];
  const float* bh0      = (const float*)d_in[11];
  const float* Wc0      = (const float*)d_in[12];
  const float* bc0      = (const float*)d_in[13];
  const float* att_W    = (const float*)d_in[14];
  const float* att_U    = (const float*)d_in[15];
  const float* att_v    = (const float*)d_in[16];

  float* outs  = (float*)d_out;
  float* w_out = outs + (size_t)BB * TT * VV;

  float* ws = (float*)d_ws;
  float* att_Ut    = ws;  ws += 1024 * 1024;
  float* att_Wt    = ws;  ws += 1024 * 2048;
  float* bg        = ws;  ws += 4096;
  float* mean_feat = ws;  ws += 64 * 2048;
  float* feat_proj = ws;  ws += 3136 * 1024;
  float* xh        = ws;  ws += 64 * XHLEN;
  float* cbuf      = ws;  ws += 64 * 1024;
  float* hU        = ws;  ws += 64 * 1024;
  float* gates     = ws;  ws += 64 * 4096;

  // ---- precompute ----
  transpose_k<<<dim3(32, 32), 256, 0, stream>>>(att_U, att_Ut, 1024, 1024);
  transpose_k<<<dim3(32, 64), 256, 0, stream>>>(att_W, att_Wt, 2048, 1024);
  setup_k<<<32, 256, 0, stream>>>(b_ih, b_hh, bg, category, xh);
  mean_k<<<512, 256, 0, stream>>>(features, mean_feat);
  // h0 -> xh h-slot ; c0 -> cbuf
  gemm_k<false><<<dim3(32, 1), 256, 0, stream>>>(mean_feat, 2048, Wh0, bh0,
                                                 xh + XKLEN, XHLEN, 1024, 2048);
  gemm_k<false><<<dim3(32, 1), 256, 0, stream>>>(mean_feat, 2048, Wc0, bc0,
                                                 cbuf, 1024, 1024, 2048);
  // feat_proj[(b,l)][a] = features @ att_W
  gemm_k<false><<<dim3(32, 49), 256, 0, stream>>>(features, 2048, att_Wt, nullptr,
                                                  feat_proj, 1024, 1024, 2048);

  // ---- timestep loop ----
  for (int t = 0; t < TT; ++t) {
    // hU = h @ att_U
    gemm_k<false><<<dim3(32, 1), 256, 0, stream>>>(xh + XKLEN, XHLEN, att_Ut, nullptr,
                                                   hU, 1024, 1024, 1024);
    // attention + context + embedding gather
    attn_k<<<64, 256, 0, stream>>>(feat_proj, hU, att_v, features,
                                   captions, emb, xh, w_out, t);
    // gates = x @ W_ih^T + (b_ih+b_hh)
    gemm_k<false><<<dim3(128, 1), 256, 0, stream>>>(xh, XHLEN, W_ih, bg,
                                                    gates, 4096, 4096, XKLEN);
    // gates += h @ W_hh^T
    gemm_k<true><<<dim3(128, 1), 256, 0, stream>>>(xh + XKLEN, XHLEN, W_hh, nullptr,
                                                   gates, 4096, 4096, 1024);
    // LSTM cell -> new h into xh h-slot, c in cbuf
    lstm_k<<<256, 256, 0, stream>>>(gates, cbuf, xh);
    // out[:, t, :] = h2 @ fc_W^T + fc_b
    gemm_k<false><<<dim3(375, 1), 256, 0, stream>>>(xh + XKLEN, XHLEN, fc_W, fc_b,
                                                    outs + (size_t)t * VV, TT * VV,
                                                    VV, 1024);
  }
}

// Round 5
// 10114.680 us; speedup vs baseline: 1.5683x; 1.5683x over previous
//
#include <hip/hip_runtime.h>
#include <hip/hip_bf16.h>

#define BB 64
#define TT 32
#define VV 12000
#define EE 512
#define FF 2048
#define CDIM 128
#define HH 1024
#define LL 49
#define XHLEN 3712   /* E + F + C + H */
#define XKLEN 2688   /* E + F + C */

typedef __attribute__((ext_vector_type(8))) short bf16x8;
typedef __attribute__((ext_vector_type(4))) float f32x4;

__device__ __forceinline__ unsigned short bf16_rn(float x) {
  unsigned u = __float_as_uint(x);
  u += 0x7FFFu + ((u >> 16) & 1u);
  return (unsigned short)(u >> 16);
}
__device__ __forceinline__ float bf16_tof(unsigned short h) {
  return __uint_as_float(((unsigned)h) << 16);
}
__device__ __forceinline__ void split2(float x, short& hi, short& lo) {
  unsigned short h = bf16_rn(x);
  float r = x - bf16_tof(h);
  hi = (short)h;
  lo = (short)bf16_rn(r);
}

// ---------------------------------------------------------------------------
// MFMA GEMM: C[M,N] = (Ah(+Al))[M,K] @ Wb[N,K]^T + bias.  All bf16 operands,
// fp32 accum. M multiple of 64, K multiple of 32. MT m-tiles/wave:
//   MT=4: BN=64, wave w = n-slice w,   m-tiles 0..3
//   MT=2: BN=32, wave w = n-slice w>>1, m-tiles (w&1)*2 .. +1
// Grid: (ceil(N/BN), M/64), 256 threads. No LDS.
// Fragment: lane l -> row (l&15), k = k0 + (l>>4)*8 + [0..7] (A and B use the
// same k mapping, so dot-product is invariant to its internal order).
// C/D: col = lane&15, row = (lane>>4)*4 + reg   [HW-verified mapping]
// ---------------------------------------------------------------------------
template<bool TWOPASS, bool SPLITOUT, int MT>
__global__ __launch_bounds__(256) void mgemm_k(
    const short* __restrict__ Ah, const short* __restrict__ Al, int lda,
    const short* __restrict__ Wb, int ldw,
    const float* __restrict__ bias,
    float* __restrict__ C, int ldc,
    short* __restrict__ Ch, short* __restrict__ Cl, int ldch,
    int N, int K)
{
  const int tid = threadIdx.x;
  const int w = tid >> 6, l = tid & 63;
  const int r = l & 15, kg = l >> 4;
  const int m0 = blockIdx.y * 64;
  const int nslice = (MT == 4) ? w : (w >> 1);
  const int mbase  = (MT == 4) ? 0 : ((w & 1) * 2);
  const int n0 = blockIdx.x * (MT * 16) + nslice * 16;
  const int nrow = n0 + r;
  const int nclmp = nrow < N ? nrow : N - 1;
  const short* wp  = Wb + (size_t)nclmp * ldw + kg * 8;
  const short* ap  = Ah + (size_t)(m0 + mbase * 16 + r) * lda + kg * 8;
  const short* alp = TWOPASS ? (Al + (size_t)(m0 + mbase * 16 + r) * lda + kg * 8)
                             : nullptr;
  f32x4 acc[MT] = {};
  for (int k0 = 0; k0 < K; k0 += 32) {
    bf16x8 bf = *(const bf16x8*)(wp + k0);
#pragma unroll
    for (int m = 0; m < MT; ++m) {
      bf16x8 af = *(const bf16x8*)(ap + (size_t)(16 * m) * lda + k0);
      acc[m] = __builtin_amdgcn_mfma_f32_16x16x32_bf16(af, bf, acc[m], 0, 0, 0);
      if (TWOPASS) {
        bf16x8 alf = *(const bf16x8*)(alp + (size_t)(16 * m) * lda + k0);
        acc[m] = __builtin_amdgcn_mfma_f32_16x16x32_bf16(alf, bf, acc[m], 0, 0, 0);
      }
    }
  }
  if (nrow < N) {
    float bv = bias ? bias[nrow] : 0.f;
#pragma unroll
    for (int m = 0; m < MT; ++m) {
#pragma unroll
      for (int q = 0; q < 4; ++q) {
        int mm = m0 + (mbase + m) * 16 + kg * 4 + q;
        float v = acc[m][q] + bv;
        if (SPLITOUT) {
          short hi, lo; split2(v, hi, lo);
          Ch[(size_t)mm * ldch + nrow] = hi;
          Cl[(size_t)mm * ldch + nrow] = lo;
        } else {
          C[(size_t)mm * ldc + nrow] = v;
        }
      }
    }
  }
}

// transpose + cast to bf16: out[C][R] = bf16(in[R][C]^T)
__global__ __launch_bounds__(256) void transpose_split_k(
    const float* __restrict__ in, short* __restrict__ out, int R, int C)
{
  __shared__ float tile[32][33];
  int bc = blockIdx.x * 32, br = blockIdx.y * 32;
  int tx = threadIdx.x & 31, ty4 = (threadIdx.x >> 5) << 2;
#pragma unroll
  for (int i = 0; i < 4; ++i) {
    int r = br + ty4 + i, c = bc + tx;
    tile[ty4 + i][tx] = (r < R && c < C) ? in[(size_t)r * C + c] : 0.f;
  }
  __syncthreads();
#pragma unroll
  for (int i = 0; i < 4; ++i) {
    int oc = bc + ty4 + i, orr = br + tx;
    if (oc < C && orr < R) out[(size_t)oc * R + orr] = (short)bf16_rn(tile[tx][ty4 + i]);
  }
}

// elementwise fp32 -> bf16
__global__ __launch_bounds__(256) void cast_k(
    const float* __restrict__ in, short* __restrict__ out, size_t n)
{
  for (size_t i = blockIdx.x * 256ULL + threadIdx.x; i < n; i += gridDim.x * 256ULL)
    out[i] = (short)bf16_rn(in[i]);
}

// Wf[n][k] = bf16( k<XKLEN ? W_ih[n][k] : W_hh[n][k-XKLEN] ). Grid (15, 4096).
__global__ __launch_bounds__(256) void concat_k(
    const float* __restrict__ wih, const float* __restrict__ whh,
    short* __restrict__ wf)
{
  int k = blockIdx.x * 256 + threadIdx.x;
  int n = blockIdx.y;
  if (k < XHLEN) {
    float v = (k < XKLEN) ? wih[(size_t)n * XKLEN + k]
                          : whh[(size_t)n * HH + (k - XKLEN)];
    wf[(size_t)n * XHLEN + k] = (short)bf16_rn(v);
  }
}

// mean over L of features -> bf16 mean_feat[B][F]. Grid 512 x 256.
__global__ __launch_bounds__(256) void mean_k(
    const float* __restrict__ feat, short* __restrict__ mf)
{
  int idx = blockIdx.x * 256 + threadIdx.x;    // B*F = 131072
  int b = idx >> 11, f = idx & 2047;
  float s = 0.f;
#pragma unroll
  for (int l = 0; l < LL; ++l) s += feat[((size_t)b * LL + l) * FF + f];
  mf[idx] = (short)bf16_rn(s * (1.f / 49.f));
}

// combined gate bias + category slot (split) of xh. Grid 32 x 256.
__global__ __launch_bounds__(256) void setup_k(
    const float* __restrict__ b_ih, const float* __restrict__ b_hh,
    float* __restrict__ bg,
    const float* __restrict__ cat,
    short* __restrict__ xh_h, short* __restrict__ xh_l)
{
  int idx = blockIdx.x * 256 + threadIdx.x;
  if (idx < 4096) bg[idx] = b_ih[idx] + b_hh[idx];
  if (idx < BB * CDIM) {
    int b = idx >> 7, j = idx & 127;
    short hi, lo; split2(cat[idx], hi, lo);
    xh_h[(size_t)b * XHLEN + EE + FF + j] = hi;
    xh_l[(size_t)b * XHLEN + EE + FF + j] = lo;
  }
}

// Fused attention: scores(tanh), softmax, context, embedding gather.
// Writes ctx+emb slots of xh (split). One block per batch row. Grid 64 x 256.
__global__ __launch_bounds__(256) void attn_k(
    const float* __restrict__ feat_proj, const float* __restrict__ hU,
    const float* __restrict__ att_v, const float* __restrict__ features,
    const int* __restrict__ captions, const float* __restrict__ emb,
    short* __restrict__ xh_h, short* __restrict__ xh_l,
    float* __restrict__ w_out, int t)
{
  int b = blockIdx.x;
  __shared__ float s_w[LL];
  int tid = threadIdx.x;
  int wave = tid >> 6, lane = tid & 63;

  for (int l = wave; l < LL; l += 4) {
    const float* fp = feat_proj + ((size_t)b * LL + l) * HH;
    const float* hu = hU + (size_t)b * HH;
    float acc = 0.f;
    for (int a = lane; a < HH; a += 64)
      acc += tanhf(fp[a] + hu[a]) * att_v[a];
#pragma unroll
    for (int off = 32; off > 0; off >>= 1) acc += __shfl_down(acc, off);
    if (lane == 0) s_w[l] = acc;
  }
  __syncthreads();

  if (wave == 0) {
    float v = (lane < LL) ? s_w[lane] : -1e30f;
    float m = v;
#pragma unroll
    for (int off = 32; off > 0; off >>= 1) m = fmaxf(m, __shfl_xor(m, off));
    float e = (lane < LL) ? expf(v - m) : 0.f;
    float s = e;
#pragma unroll
    for (int off = 32; off > 0; off >>= 1) s += __shfl_xor(s, off);
    float w = e / s;
    if (lane < LL) {
      s_w[lane] = w;
      w_out[((size_t)b * TT + t) * LL + lane] = w;
    }
  }
  __syncthreads();

  for (int f = tid; f < FF; f += 256) {
    float acc = 0.f;
#pragma unroll
    for (int l = 0; l < LL; ++l)
      acc += s_w[l] * features[((size_t)b * LL + l) * FF + f];
    short hi, lo; split2(acc, hi, lo);
    xh_h[(size_t)b * XHLEN + EE + f] = hi;
    xh_l[(size_t)b * XHLEN + EE + f] = lo;
  }

  int cap = captions[b * TT + t];
  for (int j = tid; j < EE; j += 256) {
    short hi, lo; split2(emb[(size_t)cap * EE + j], hi, lo);
    xh_h[(size_t)b * XHLEN + j] = hi;
    xh_l[(size_t)b * XHLEN + j] = lo;
  }
}

// LSTM cell elementwise; writes new h (split) into xh. Grid 256 x 256.
__global__ __launch_bounds__(256) void lstm_k(
    const float* __restrict__ gates, float* __restrict__ c,
    short* __restrict__ xh_h, short* __restrict__ xh_l)
{
  int idx = blockIdx.x * 256 + threadIdx.x;   // B*H
  int b = idx >> 10, j = idx & 1023;
  const float* g = gates + (size_t)b * 4096;
  float ig = g[j], fg = g[HH + j], gg = g[2 * HH + j], og = g[3 * HH + j];
  float si = 1.f / (1.f + expf(-ig));
  float sf = 1.f / (1.f + expf(-fg));
  float so = 1.f / (1.f + expf(-og));
  float cc = sf * c[idx] + si * tanhf(gg);
  float hh = so * tanhf(cc);
  c[idx] = cc;
  short hi, lo; split2(hh, hi, lo);
  xh_h[(size_t)b * XHLEN + XKLEN + j] = hi;
  xh_l[(size_t)b * XHLEN + XKLEN + j] = lo;
}

extern "C" void kernel_launch(void* const* d_in, const int* in_sizes, int n_in,
                              void* d_out, int out_size, void* d_ws, size_t ws_size,
                              hipStream_t stream) {
  const int*   captions = (const int*)  d_in[0];
  const float* features = (const float*)d_in[1];
  const float* category = (const float*)d_in[2];
  const float* emb      = (const float*)d_in[3];
  const float* W_ih     = (const float*)d_in[4];
  const float* b_ih     = (const float*)d_in[5];
  const float* W_hh     = (const float*)d_in[6];
  const float* b_hh     = (const float*)d_in[7];
  const float* fc_W     = (const float*)d_in[8];
  const float* fc_b     = (const float*)d_in[9];
  const float* Wh0      = (const float*)d_in[10];
  const float* bh0      = (const float*)d_in[11];
  const float* Wc0      = (const float*)d_in[12];
  const float* bc0      = (const float*)d_in[13];
  const float* att_W    = (const float*)d_in[14];
  const float* att_U    = (const float*)d_in[15];
  const float* att_v    = (const float*)d_in[16];

  float* outs  = (float*)d_out;
  float* w_out = outs + (size_t)BB * TT * VV;

  char* p = (char*)d_ws;
  auto alloc = [&](size_t bytes) {
    char* q = p; p += (bytes + 255) & ~(size_t)255; return q;
  };
  short* attUt = (short*)alloc((size_t)HH * HH * 2);        // att_U^T   bf16
  short* attWt = (short*)alloc((size_t)HH * FF * 2);        // att_W^T   bf16
  short* featb = (short*)alloc((size_t)BB * LL * FF * 2);   // features  bf16
  short* fcWb  = (short*)alloc((size_t)VV * HH * 2);        // fc_W      bf16
  short* Wfb   = (short*)alloc((size_t)4096 * XHLEN * 2);   // [W_ih|W_hh] bf16
  short* Wh0b  = (short*)alloc((size_t)HH * FF * 2);
  short* Wc0b  = (short*)alloc((size_t)HH * FF * 2);
  short* mfb   = (short*)alloc((size_t)BB * FF * 2);        // mean_feat bf16
  short* xh_h  = (short*)alloc((size_t)BB * XHLEN * 2);     // [emb|ctx|cat|h] hi
  short* xh_l  = (short*)alloc((size_t)BB * XHLEN * 2);     // lo
  float* featp = (float*)alloc((size_t)BB * LL * HH * 4);   // feat_proj fp32
  float* cbuf  = (float*)alloc((size_t)BB * HH * 4);
  float* hU    = (float*)alloc((size_t)BB * HH * 4);
  float* gates = (float*)alloc((size_t)BB * 4096 * 4);
  float* bg    = (float*)alloc(4096 * 4);

  // ---- one-time prep ----
  transpose_split_k<<<dim3(32, 32), 256, 0, stream>>>(att_U, attUt, HH, HH);
  transpose_split_k<<<dim3(32, 64), 256, 0, stream>>>(att_W, attWt, FF, HH);
  cast_k<<<2048, 256, 0, stream>>>(features, featb, (size_t)BB * LL * FF);
  cast_k<<<2048, 256, 0, stream>>>(fc_W, fcWb, (size_t)VV * HH);
  cast_k<<<1024, 256, 0, stream>>>(Wh0, Wh0b, (size_t)HH * FF);
  cast_k<<<1024, 256, 0, stream>>>(Wc0, Wc0b, (size_t)HH * FF);
  concat_k<<<dim3(15, 4096), 256, 0, stream>>>(W_ih, W_hh, Wfb);
  setup_k<<<32, 256, 0, stream>>>(b_ih, b_hh, bg, category, xh_h, xh_l);
  mean_k<<<512, 256, 0, stream>>>(features, mfb);

  // h0 (split into xh) and c0
  mgemm_k<false, true, 2><<<dim3(32, 1), 256, 0, stream>>>(
      mfb, nullptr, FF, Wh0b, FF, bh0,
      nullptr, 0, xh_h + XKLEN, xh_l + XKLEN, XHLEN, HH, FF);
  mgemm_k<false, false, 2><<<dim3(32, 1), 256, 0, stream>>>(
      mfb, nullptr, FF, Wc0b, FF, bc0,
      cbuf, HH, nullptr, nullptr, 0, HH, FF);
  // feat_proj = features @ att_W   [3136 x 1024]
  mgemm_k<false, false, 4><<<dim3(16, 49), 256, 0, stream>>>(
      featb, nullptr, FF, attWt, FF, nullptr,
      featp, HH, nullptr, nullptr, 0, HH, FF);

  // ---- timestep loop ----
  for (int t = 0; t < TT; ++t) {
    // hU = h @ att_U
    mgemm_k<true, false, 2><<<dim3(32, 1), 256, 0, stream>>>(
        xh_h + XKLEN, xh_l + XKLEN, XHLEN, attUt, HH, nullptr,
        hU, HH, nullptr, nullptr, 0, HH, HH);
    // attention + context + embedding gather (writes xh split slots)
    attn_k<<<64, 256, 0, stream>>>(featp, hU, att_v, features,
                                   captions, emb, xh_h, xh_l, w_out, t);
    // gates = [x|h] @ [W_ih|W_hh]^T + (b_ih+b_hh)
    mgemm_k<true, false, 2><<<dim3(128, 1), 256, 0, stream>>>(
        xh_h, xh_l, XHLEN, Wfb, XHLEN, bg,
        gates, 4096, nullptr, nullptr, 0, 4096, XHLEN);
    // LSTM cell -> new h (split) into xh, c in cbuf
    lstm_k<<<256, 256, 0, stream>>>(gates, cbuf, xh_h, xh_l);
    // out[:, t, :] = h2 @ fc_W^T + fc_b
    mgemm_k<true, false, 2><<<dim3(375, 1), 256, 0, stream>>>(
        xh_h + XKLEN, xh_l + XKLEN, XHLEN, fcWb, HH, fc_b,
        outs + (size_t)t * VV, TT * VV, nullptr, nullptr, 0, VV, HH);
  }
}

// Round 7
// 8110.957 us; speedup vs baseline: 1.9558x; 1.2470x over previous
//
#include <hip/hip_runtime.h>
#include <hip/hip_bf16.h>

#define BB 64
#define TT 32
#define VV 12000
#define EE 512
#define FF 2048
#define CDIM 128
#define HH 1024
#define LL 49
#define XHLEN 3712   /* E + F + C + H */
#define XKLEN 2688   /* E + F + C */

typedef __attribute__((ext_vector_type(8))) short bf16x8;
typedef __attribute__((ext_vector_type(4))) float f32x4;

__device__ __forceinline__ unsigned short bf16_rn(float x) {
  unsigned u = __float_as_uint(x);
  u += 0x7FFFu + ((u >> 16) & 1u);
  return (unsigned short)(u >> 16);
}
__device__ __forceinline__ float bf16_tof(unsigned short h) {
  return __uint_as_float(((unsigned)h) << 16);
}
__device__ __forceinline__ void split2(float x, short& hi, short& lo) {
  unsigned short h = bf16_rn(x);
  float r = x - bf16_tof(h);
  hi = (short)h;
  lo = (short)bf16_rn(r);
}

// ---------------------------------------------------------------------------
// Small-M GEMM, K-split across the 4 waves + LDS reduce (for latency-bound
// per-step GEMMs). C[64,N] = (Ah+Al)[64,K] @ Wb[N,K]^T + bias.
// Block: 256 thr; grid.x = N/16. Each block owns a 64x16 output tile; wave w
// computes the partial over k in [w*K/4, (w+1)*K/4). K % 128 == 0.
// Fragment rows: A row = m*16 + r, W row = n0 + r (r = lane&15).
// C/D mapping: col = lane&15, row(within m-tile) = (lane>>4)*4 + q.
// ---------------------------------------------------------------------------
template<bool TWOPASS>
__global__ __launch_bounds__(256) void skgemm_k(
    const short* __restrict__ Ah, const short* __restrict__ Al, int lda,
    const short* __restrict__ Wb, int ldw,
    const float* __restrict__ bias,
    float* __restrict__ C, int ldc, int K)
{
  __shared__ float red[4][64][17];   // [wave][src lane][m*4+q], padded
  const int tid = threadIdx.x;
  const int w = tid >> 6, l = tid & 63;
  const int r = l & 15, kg = l >> 4;
  const int n0 = blockIdx.x * 16;
  const int nrow = n0 + r;
  const int kc = K >> 2;
  const int kb = w * kc;
  const short* wp  = Wb + (size_t)nrow * ldw + kb + kg * 8;
  const short* ap  = Ah + (size_t)r * lda + kb + kg * 8;
  const short* alp = TWOPASS ? (Al + (size_t)r * lda + kb + kg * 8) : nullptr;
  f32x4 acc[4] = {};
  for (int k0 = 0; k0 < kc; k0 += 32) {
    bf16x8 bf = *(const bf16x8*)(wp + k0);
#pragma unroll
    for (int m = 0; m < 4; ++m) {
      bf16x8 af = *(const bf16x8*)(ap + (size_t)(16 * m) * lda + k0);
      acc[m] = __builtin_amdgcn_mfma_f32_16x16x32_bf16(af, bf, acc[m], 0, 0, 0);
      if (TWOPASS) {
        bf16x8 alf = *(const bf16x8*)(alp + (size_t)(16 * m) * lda + k0);
        acc[m] = __builtin_amdgcn_mfma_f32_16x16x32_bf16(alf, bf, acc[m], 0, 0, 0);
      }
    }
  }
#pragma unroll
  for (int m = 0; m < 4; ++m)
#pragma unroll
    for (int q = 0; q < 4; ++q)
      red[w][l][m * 4 + q] = acc[m][q];
  __syncthreads();
  // epilogue: thread t -> output row t>>2, cols n0 + (t&3)*4 .. +3
  const int row = tid >> 2, cg = (tid & 3) * 4;
  const int m = row >> 4, kq = row & 15;
  float4 o;
  float* po = &o.x;
#pragma unroll
  for (int cc = 0; cc < 4; ++cc) {
    int c = cg + cc;
    int sl = (kq >> 2) * 16 + c;                  // source lane = kg*16 + col
    int ii = m * 4 + (kq & 3);
    float s = red[0][sl][ii] + red[1][sl][ii] + red[2][sl][ii] + red[3][sl][ii];
    po[cc] = s + (bias ? bias[n0 + c] : 0.f);
  }
  *(float4*)&C[(size_t)row * ldc + n0 + cg] = o;
}

// ---------------------------------------------------------------------------
// Batched fc GEMM over all timesteps: Hall[T*B, H] @ fcW[V,H]^T + fc_b.
// Hall row = t*64 + b. blockIdx.y == t (64-row m-tile). 4 waves x 16 n-rows,
// MT=4 m-tiles per wave, hi/lo two-pass. Grid (188, 32).
// ---------------------------------------------------------------------------
__global__ __launch_bounds__(256) void bgemm_k(
    const short* __restrict__ Ah, const short* __restrict__ Al,
    const short* __restrict__ Wb, const float* __restrict__ bias,
    float* __restrict__ outs)
{
  const int tid = threadIdx.x;
  const int w = tid >> 6, l = tid & 63;
  const int r = l & 15, kg = l >> 4;
  const int t = blockIdx.y;
  const int m0 = t * 64;
  const int nrow = blockIdx.x * 64 + w * 16 + r;
  const int nc = nrow < VV ? nrow : VV - 1;
  const short* wp  = Wb + (size_t)nc * HH + kg * 8;
  const short* ap  = Ah + (size_t)(m0 + r) * HH + kg * 8;
  const short* alp = Al + (size_t)(m0 + r) * HH + kg * 8;
  f32x4 acc[4] = {};
  for (int k0 = 0; k0 < HH; k0 += 32) {
    bf16x8 bf = *(const bf16x8*)(wp + k0);
#pragma unroll
    for (int m = 0; m < 4; ++m) {
      bf16x8 af = *(const bf16x8*)(ap + (size_t)(16 * m) * HH + k0);
      acc[m] = __builtin_amdgcn_mfma_f32_16x16x32_bf16(af, bf, acc[m], 0, 0, 0);
      bf16x8 alf = *(const bf16x8*)(alp + (size_t)(16 * m) * HH + k0);
      acc[m] = __builtin_amdgcn_mfma_f32_16x16x32_bf16(alf, bf, acc[m], 0, 0, 0);
    }
  }
  if (nrow < VV) {
    float bv = bias[nrow];
#pragma unroll
    for (int m = 0; m < 4; ++m)
#pragma unroll
      for (int q = 0; q < 4; ++q) {
        int b = m * 16 + kg * 4 + q;             // batch index within tile
        outs[((size_t)b * TT + t) * VV + nrow] = acc[m][q] + bv;
      }
  }
}

// ---------------------------------------------------------------------------
// MFMA GEMM used in one-time prep (h0, c0, feat_proj). Same as round 5.
// ---------------------------------------------------------------------------
template<bool TWOPASS, bool SPLITOUT, int MT>
__global__ __launch_bounds__(256) void mgemm_k(
    const short* __restrict__ Ah, const short* __restrict__ Al, int lda,
    const short* __restrict__ Wb, int ldw,
    const float* __restrict__ bias,
    float* __restrict__ C, int ldc,
    short* __restrict__ Ch, short* __restrict__ Cl, int ldch,
    int N, int K)
{
  const int tid = threadIdx.x;
  const int w = tid >> 6, l = tid & 63;
  const int r = l & 15, kg = l >> 4;
  const int m0 = blockIdx.y * 64;
  const int nslice = (MT == 4) ? w : (w >> 1);
  const int mbase  = (MT == 4) ? 0 : ((w & 1) * 2);
  const int n0 = blockIdx.x * (MT * 16) + nslice * 16;
  const int nrow = n0 + r;
  const int nclmp = nrow < N ? nrow : N - 1;
  const short* wp  = Wb + (size_t)nclmp * ldw + kg * 8;
  const short* ap  = Ah + (size_t)(m0 + mbase * 16 + r) * lda + kg * 8;
  const short* alp = TWOPASS ? (Al + (size_t)(m0 + mbase * 16 + r) * lda + kg * 8)
                             : nullptr;
  f32x4 acc[MT] = {};
  for (int k0 = 0; k0 < K; k0 += 32) {
    bf16x8 bf = *(const bf16x8*)(wp + k0);
#pragma unroll
    for (int m = 0; m < MT; ++m) {
      bf16x8 af = *(const bf16x8*)(ap + (size_t)(16 * m) * lda + k0);
      acc[m] = __builtin_amdgcn_mfma_f32_16x16x32_bf16(af, bf, acc[m], 0, 0, 0);
      if (TWOPASS) {
        bf16x8 alf = *(const bf16x8*)(alp + (size_t)(16 * m) * lda + k0);
        acc[m] = __builtin_amdgcn_mfma_f32_16x16x32_bf16(alf, bf, acc[m], 0, 0, 0);
      }
    }
  }
  if (nrow < N) {
    float bv = bias ? bias[nrow] : 0.f;
#pragma unroll
    for (int m = 0; m < MT; ++m) {
#pragma unroll
      for (int q = 0; q < 4; ++q) {
        int mm = m0 + (mbase + m) * 16 + kg * 4 + q;
        float v = acc[m][q] + bv;
        if (SPLITOUT) {
          short hi, lo; split2(v, hi, lo);
          Ch[(size_t)mm * ldch + nrow] = hi;
          Cl[(size_t)mm * ldch + nrow] = lo;
        } else {
          C[(size_t)mm * ldc + nrow] = v;
        }
      }
    }
  }
}

// transpose + cast to bf16: out[C][R] = bf16(in[R][C]^T)
__global__ __launch_bounds__(256) void transpose_split_k(
    const float* __restrict__ in, short* __restrict__ out, int R, int C)
{
  __shared__ float tile[32][33];
  int bc = blockIdx.x * 32, br = blockIdx.y * 32;
  int tx = threadIdx.x & 31, ty4 = (threadIdx.x >> 5) << 2;
#pragma unroll
  for (int i = 0; i < 4; ++i) {
    int r = br + ty4 + i, c = bc + tx;
    tile[ty4 + i][tx] = (r < R && c < C) ? in[(size_t)r * C + c] : 0.f;
  }
  __syncthreads();
#pragma unroll
  for (int i = 0; i < 4; ++i) {
    int oc = bc + ty4 + i, orr = br + tx;
    if (oc < C && orr < R) out[(size_t)oc * R + orr] = (short)bf16_rn(tile[tx][ty4 + i]);
  }
}

__global__ __launch_bounds__(256) void cast_k(
    const float* __restrict__ in, short* __restrict__ out, size_t n)
{
  for (size_t i = blockIdx.x * 256ULL + threadIdx.x; i < n; i += gridDim.x * 256ULL)
    out[i] = (short)bf16_rn(in[i]);
}

// Wf[n][k] = bf16( k<XKLEN ? W_ih[n][k] : W_hh[n][k-XKLEN] ). Grid (15, 4096).
__global__ __launch_bounds__(256) void concat_k(
    const float* __restrict__ wih, const float* __restrict__ whh,
    short* __restrict__ wf)
{
  int k = blockIdx.x * 256 + threadIdx.x;
  int n = blockIdx.y;
  if (k < XHLEN) {
    float v = (k < XKLEN) ? wih[(size_t)n * XKLEN + k]
                          : whh[(size_t)n * HH + (k - XKLEN)];
    wf[(size_t)n * XHLEN + k] = (short)bf16_rn(v);
  }
}

__global__ __launch_bounds__(256) void mean_k(
    const float* __restrict__ feat, short* __restrict__ mf)
{
  int idx = blockIdx.x * 256 + threadIdx.x;    // B*F
  int b = idx >> 11, f = idx & 2047;
  float s = 0.f;
#pragma unroll
  for (int l = 0; l < LL; ++l) s += feat[((size_t)b * LL + l) * FF + f];
  mf[idx] = (short)bf16_rn(s * (1.f / 49.f));
}

__global__ __launch_bounds__(256) void setup_k(
    const float* __restrict__ b_ih, const float* __restrict__ b_hh,
    float* __restrict__ bg,
    const float* __restrict__ cat,
    short* __restrict__ xh_h, short* __restrict__ xh_l)
{
  int idx = blockIdx.x * 256 + threadIdx.x;
  if (idx < 4096) bg[idx] = b_ih[idx] + b_hh[idx];
  if (idx < BB * CDIM) {
    int b = idx >> 7, j = idx & 127;
    short hi, lo; split2(cat[idx], hi, lo);
    xh_h[(size_t)b * XHLEN + EE + FF + j] = hi;
    xh_l[(size_t)b * XHLEN + EE + FF + j] = lo;
  }
}

// Fused attention: scores(tanh), softmax, context, embedding gather.
__global__ __launch_bounds__(256) void attn_k(
    const float* __restrict__ feat_proj, const float* __restrict__ hU,
    const float* __restrict__ att_v, const float* __restrict__ features,
    const int* __restrict__ captions, const float* __restrict__ emb,
    short* __restrict__ xh_h, short* __restrict__ xh_l,
    float* __restrict__ w_out, int t)
{
  int b = blockIdx.x;
  __shared__ float s_w[LL];
  int tid = threadIdx.x;
  int wave = tid >> 6, lane = tid & 63;

  for (int l = wave; l < LL; l += 4) {
    const float* fp = feat_proj + ((size_t)b * LL + l) * HH;
    const float* hu = hU + (size_t)b * HH;
    float acc = 0.f;
    for (int a = lane; a < HH; a += 64)
      acc += tanhf(fp[a] + hu[a]) * att_v[a];
#pragma unroll
    for (int off = 32; off > 0; off >>= 1) acc += __shfl_down(acc, off);
    if (lane == 0) s_w[l] = acc;
  }
  __syncthreads();

  if (wave == 0) {
    float v = (lane < LL) ? s_w[lane] : -1e30f;
    float m = v;
#pragma unroll
    for (int off = 32; off > 0; off >>= 1) m = fmaxf(m, __shfl_xor(m, off));
    float e = (lane < LL) ? expf(v - m) : 0.f;
    float s = e;
#pragma unroll
    for (int off = 32; off > 0; off >>= 1) s += __shfl_xor(s, off);
    float w = e / s;
    if (lane < LL) {
      s_w[lane] = w;
      w_out[((size_t)b * TT + t) * LL + lane] = w;
    }
  }
  __syncthreads();

  for (int f = tid; f < FF; f += 256) {
    float acc = 0.f;
#pragma unroll
    for (int l = 0; l < LL; ++l)
      acc += s_w[l] * features[((size_t)b * LL + l) * FF + f];
    short hi, lo; split2(acc, hi, lo);
    xh_h[(size_t)b * XHLEN + EE + f] = hi;
    xh_l[(size_t)b * XHLEN + EE + f] = lo;
  }

  int cap = captions[b * TT + t];
  for (int j = tid; j < EE; j += 256) {
    short hi, lo; split2(emb[(size_t)cap * EE + j], hi, lo);
    xh_h[(size_t)b * XHLEN + j] = hi;
    xh_l[(size_t)b * XHLEN + j] = lo;
  }
}

// LSTM cell; writes new h (split) into xh AND into the h-history Hall.
__global__ __launch_bounds__(256) void lstm_k(
    const float* __restrict__ gates, float* __restrict__ c,
    short* __restrict__ xh_h, short* __restrict__ xh_l,
    short* __restrict__ hall_h, short* __restrict__ hall_l, int t)
{
  int idx = blockIdx.x * 256 + threadIdx.x;   // B*H
  int b = idx >> 10, j = idx & 1023;
  const float* g = gates + (size_t)b * 4096;
  float ig = g[j], fg = g[HH + j], gg = g[2 * HH + j], og = g[3 * HH + j];
  float si = 1.f / (1.f + expf(-ig));
  float sf = 1.f / (1.f + expf(-fg));
  float so = 1.f / (1.f + expf(-og));
  float cc = sf * c[idx] + si * tanhf(gg);
  float hh = so * tanhf(cc);
  c[idx] = cc;
  short hi, lo; split2(hh, hi, lo);
  xh_h[(size_t)b * XHLEN + XKLEN + j] = hi;
  xh_l[(size_t)b * XHLEN + XKLEN + j] = lo;
  size_t ho = ((size_t)t * BB + b) * HH + j;
  hall_h[ho] = hi;
  hall_l[ho] = lo;
}

extern "C" void kernel_launch(void* const* d_in, const int* in_sizes, int n_in,
                              void* d_out, int out_size, void* d_ws, size_t ws_size,
                              hipStream_t stream) {
  const int*   captions = (const int*)  d_in[0];
  const float* features = (const float*)d_in[1];
  const float* category = (const float*)d_in[2];
  const float* emb      = (const float*)d_in[3];
  const float* W_ih     = (const float*)d_in[4];
  const float* b_ih     = (const float*)d_in[5];
  const float* W_hh     = (const float*)d_in[6];
  const float* b_hh     = (const float*)d_in[7];
  const float* fc_W     = (const float*)d_in[8];
  const float* fc_b     = (const float*)d_in[9];
  const float* Wh0      = (const float*)d_in[10];
  const float* bh0      = (const float*)d_in[11];
  const float* Wc0      = (const float*)d_in[12];
  const float* bc0      = (const float*)d_in[13];
  const float* att_W    = (const float*)d_in[14];
  const float* att_U    = (const float*)d_in[15];
  const float* att_v    = (const float*)d_in[16];

  float* outs  = (float*)d_out;
  float* w_out = outs + (size_t)BB * TT * VV;

  char* p = (char*)d_ws;
  auto alloc = [&](size_t bytes) {
    char* q = p; p += (bytes + 255) & ~(size_t)255; return q;
  };
  short* attUt = (short*)alloc((size_t)HH * HH * 2);        // att_U^T   bf16
  short* attWt = (short*)alloc((size_t)HH * FF * 2);        // att_W^T   bf16
  short* featb = (short*)alloc((size_t)BB * LL * FF * 2);   // features  bf16 (prep only)
  short* fcWb  = (short*)alloc((size_t)VV * HH * 2);        // fc_W      bf16
  short* Wfb   = (short*)alloc((size_t)4096 * XHLEN * 2);   // [W_ih|W_hh] bf16
  short* Wh0b  = (short*)alloc((size_t)HH * FF * 2);
  short* Wc0b  = (short*)alloc((size_t)HH * FF * 2);
  short* mfb   = (short*)alloc((size_t)BB * FF * 2);        // mean_feat bf16
  short* xh_h  = (short*)alloc((size_t)BB * XHLEN * 2);     // [emb|ctx|cat|h] hi
  short* xh_l  = (short*)alloc((size_t)BB * XHLEN * 2);     // lo
  float* featp = (float*)alloc((size_t)BB * LL * HH * 4);   // feat_proj fp32
  float* cbuf  = (float*)alloc((size_t)BB * HH * 4);
  float* hU    = (float*)alloc((size_t)BB * HH * 4);
  float* gates = (float*)alloc((size_t)BB * 4096 * 4);
  float* bg    = (float*)alloc(4096 * 4);
  // h2 history for the deferred batched fc GEMM; aliases featb (featb is
  // dead after the feat_proj prep GEMM, Hall is written only inside the loop).
  short* hall_h = featb;
  short* hall_l = featb + (size_t)TT * BB * HH;

  // ---- one-time prep ----
  transpose_split_k<<<dim3(32, 32), 256, 0, stream>>>(att_U, attUt, HH, HH);
  transpose_split_k<<<dim3(32, 64), 256, 0, stream>>>(att_W, attWt, FF, HH);
  cast_k<<<2048, 256, 0, stream>>>(features, featb, (size_t)BB * LL * FF);
  cast_k<<<2048, 256, 0, stream>>>(fc_W, fcWb, (size_t)VV * HH);
  cast_k<<<1024, 256, 0, stream>>>(Wh0, Wh0b, (size_t)HH * FF);
  cast_k<<<1024, 256, 0, stream>>>(Wc0, Wc0b, (size_t)HH * FF);
  concat_k<<<dim3(15, 4096), 256, 0, stream>>>(W_ih, W_hh, Wfb);
  setup_k<<<32, 256, 0, stream>>>(b_ih, b_hh, bg, category, xh_h, xh_l);
  mean_k<<<512, 256, 0, stream>>>(features, mfb);

  // h0 (split into xh) and c0
  mgemm_k<false, true, 2><<<dim3(32, 1), 256, 0, stream>>>(
      mfb, nullptr, FF, Wh0b, FF, bh0,
      nullptr, 0, xh_h + XKLEN, xh_l + XKLEN, XHLEN, HH, FF);
  mgemm_k<false, false, 2><<<dim3(32, 1), 256, 0, stream>>>(
      mfb, nullptr, FF, Wc0b, FF, bc0,
      cbuf, HH, nullptr, nullptr, 0, HH, FF);
  // feat_proj = features @ att_W   [3136 x 1024]  (last reader of featb)
  mgemm_k<false, false, 4><<<dim3(16, 49), 256, 0, stream>>>(
      featb, nullptr, FF, attWt, FF, nullptr,
      featp, HH, nullptr, nullptr, 0, HH, FF);

  // ---- timestep loop (4 launches/step; fc deferred) ----
  for (int t = 0; t < TT; ++t) {
    // hU = h @ att_U        (N=1024, K=1024, wave-K-split)
    skgemm_k<true><<<64, 256, 0, stream>>>(
        xh_h + XKLEN, xh_l + XKLEN, XHLEN, attUt, HH, nullptr, hU, HH, HH);
    // attention + context + embedding gather
    attn_k<<<BB, 256, 0, stream>>>(featp, hU, att_v, features,
                                   captions, emb, xh_h, xh_l, w_out, t);
    // gates = [x|h] @ [W_ih|W_hh]^T + (b_ih+b_hh)   (N=4096, K=3712)
    skgemm_k<true><<<256, 256, 0, stream>>>(
        xh_h, xh_l, XHLEN, Wfb, XHLEN, bg, gates, 4096, XHLEN);
    // LSTM cell -> new h into xh + Hall, c in cbuf
    lstm_k<<<256, 256, 0, stream>>>(gates, cbuf, xh_h, xh_l,
                                    hall_h, hall_l, t);
  }

  // ---- deferred batched fc: out[b,t,:] = h2[t,b] @ fc_W^T + fc_b ----
  bgemm_k<<<dim3(188, TT), 256, 0, stream>>>(hall_h, hall_l, fcWb, fc_b, outs);
}